// Round 9
// baseline (553.755 us; speedup 1.0000x reference)
//
#include <hip/hip_runtime.h>

#define NFEAT 128
#define NGRAPHS 128
#define FCH 64
#define NCLS 10
#define ELLW 48
#define NSL 8      // feature slices (one per XCD)
#define SLF 16     // floats per slice
#define AGG_CH 64  // nodes per aggregate block chunk

// ---------------- ELL fill: cursor[d]++ allocates slot --------------
__global__ void ell_fill_kernel(const int* __restrict__ src, const int* __restrict__ dst, int E,
                                int* __restrict__ cursor, int* __restrict__ ell) {
    int i = (blockIdx.x * blockDim.x + threadIdx.x) * 4;
    if (i + 3 < E) {
        int4 s4 = *(const int4*)(src + i);
        int4 d4 = *(const int4*)(dst + i);
        int p;
        p = atomicAdd(&cursor[d4.x], 1); if (p < ELLW) ell[(size_t)d4.x * ELLW + p] = s4.x;
        p = atomicAdd(&cursor[d4.y], 1); if (p < ELLW) ell[(size_t)d4.y * ELLW + p] = s4.y;
        p = atomicAdd(&cursor[d4.z], 1); if (p < ELLW) ell[(size_t)d4.z * ELLW + p] = s4.z;
        p = atomicAdd(&cursor[d4.w], 1); if (p < ELLW) ell[(size_t)d4.w * ELLW + p] = s4.w;
    } else {
        for (int j = i; j < E; ++j) {
            int d = dst[j];
            int p = atomicAdd(&cursor[d], 1);
            if (p < ELLW) ell[(size_t)d * ELLW + p] = src[j];
        }
    }
}

// ---------------- dinv = rsqrt(deg + 1) (self loop included) --------
__global__ void dinv_kernel(const int* __restrict__ deg, float* __restrict__ dinv, int N) {
    int i = blockIdx.x * blockDim.x + threadIdx.x;
    if (i < N) dinv[i] = rsqrtf((float)(deg[i] + 1));
}

// ---- GEMM: h'[r,:] = dinv[r] * (X[r,:] @ W), SLICE-MAJOR output ----
// Hs layout: [NSL][N][SLF].  256 threads, 128 rows/block, 8x8 micro-tile.
__global__ __launch_bounds__(256)
void gemm128_kernel(const float* __restrict__ X, const float* __restrict__ W,
                    const float* __restrict__ dinv, float* __restrict__ Hs, int N) {
    __shared__ float Ws[128 * 128];  // 64 KB
    int t = threadIdx.x;
    {   // cooperative W load, float4
        const float4* W4 = (const float4*)W;
        float4* Ws4 = (float4*)Ws;
        #pragma unroll
        for (int i = 0; i < 16; ++i) Ws4[t + i * 256] = W4[t + i * 256];
    }
    __syncthreads();

    int tx = t & 15;   // col group: cols tx*8 .. tx*8+7
    int ty = t >> 4;   // row group: 8 rows
    int r0 = blockIdx.x * 128 + ty * 8;

    const float* xr[8];
    bool rowok[8];
    #pragma unroll
    for (int i = 0; i < 8; ++i) {
        rowok[i] = (r0 + i < N);
        xr[i] = X + (size_t)(rowok[i] ? (r0 + i) : 0) * NFEAT;
    }

    float acc[8][8];
    #pragma unroll
    for (int i = 0; i < 8; ++i)
        #pragma unroll
        for (int j = 0; j < 8; ++j) acc[i][j] = 0.f;

    for (int k = 0; k < 128; k += 4) {
        float xk[8][4];
        #pragma unroll
        for (int i = 0; i < 8; ++i) {
            float4 v = *(const float4*)(xr[i] + k);   // broadcast across 16 lanes
            xk[i][0] = v.x; xk[i][1] = v.y; xk[i][2] = v.z; xk[i][3] = v.w;
        }
        #pragma unroll
        for (int kk = 0; kk < 4; ++kk) {
            const float* wp = &Ws[(k + kk) * 128 + (tx << 3)];
            float4 wa = *(const float4*)wp;
            float4 wb = *(const float4*)(wp + 4);
            float w[8] = {wa.x, wa.y, wa.z, wa.w, wb.x, wb.y, wb.z, wb.w};
            #pragma unroll
            for (int i = 0; i < 8; ++i) {
                float xv = xk[i][kk];
                #pragma unroll
                for (int j = 0; j < 8; ++j) acc[i][j] = fmaf(xv, w[j], acc[i][j]);
            }
        }
    }

    // epilogue: prescale by dinv, scatter into slice-major layout
    int sl = tx >> 1;            // slice of this col group
    int ofs = (tx & 1) * 8;      // offset within the 16-float slice
    #pragma unroll
    for (int i = 0; i < 8; ++i) {
        if (rowok[i]) {
            float di = dinv[r0 + i];
            float* hp = Hs + ((size_t)sl * N + (r0 + i)) * SLF + ofs;
            float4 o0 = {di * acc[i][0], di * acc[i][1], di * acc[i][2], di * acc[i][3]};
            float4 o1 = {di * acc[i][4], di * acc[i][5], di * acc[i][6], di * acc[i][7]};
            *(float4*)hp = o0;
            *(float4*)(hp + 4) = o1;
        }
    }
}

// ------- pull aggregation, slice-major Hs, XCD-affine slices --------
// block b: slice s = b&7 (XCD affinity), node chunk c = b>>3.
// wave = one node; lane = edge-group(16) x quad(4); 16 edges in flight.
// out[i, s*16+..] = relu( dinv[i]*( h'[i] + sum_s h'[src] ) + b )  (row-major out)
__global__ __launch_bounds__(256)
void aggregate_kernel(const float* __restrict__ Hs, const int* __restrict__ deg,
                      const int* __restrict__ ell, const float* __restrict__ dinv,
                      const float* __restrict__ bias, float* __restrict__ out, int N) {
    int s = blockIdx.x & (NSL - 1);
    int chunk = blockIdx.x >> 3;
    int wave = threadIdx.x >> 6;
    int lane = threadIdx.x & 63;
    int eg = lane >> 2;      // edge group 0..15
    int q = lane & 3;        // float4 slot within slice

    const float4* Hq = (const float4*)(Hs + (size_t)s * N * SLF);  // [N][4] float4
    float4 bsl = ((const float4*)bias)[s * 4 + q];

    int n0 = chunk * AGG_CH;
    int n1 = n0 + AGG_CH; if (n1 > N) n1 = N;

    for (int node = n0 + wave; node < n1; node += 4) {
        int d = deg[node]; if (d > ELLW) d = ELLW;
        const int* row = ell + (size_t)node * ELLW;

        float4 acc = {0.f, 0.f, 0.f, 0.f};
        for (int base = 0; base < d; base += 16) {
            int e = base + eg;
            if (e < d) {
                int sidx = row[e];
                float4 v = Hq[(size_t)sidx * 4 + q];
                acc.x += v.x; acc.y += v.y; acc.z += v.z; acc.w += v.w;
            }
        }
        // reduce over the 16 edge groups (lane bits 2..5)
        #pragma unroll
        for (int m = 4; m <= 32; m <<= 1) {
            acc.x += __shfl_xor(acc.x, m, 64);
            acc.y += __shfl_xor(acc.y, m, 64);
            acc.z += __shfl_xor(acc.z, m, 64);
            acc.w += __shfl_xor(acc.w, m, 64);
        }
        if (eg == 0) {
            float di = dinv[node];
            float4 self = Hq[(size_t)node * 4 + q];
            float4 o;
            o.x = fmaxf(fmaf(di, acc.x + self.x, bsl.x), 0.f);
            o.y = fmaxf(fmaf(di, acc.y + self.y, bsl.y), 0.f);
            o.z = fmaxf(fmaf(di, acc.z + self.z, bsl.z), 0.f);
            o.w = fmaxf(fmaf(di, acc.w + self.w, bsl.w), 0.f);
            ((float4*)(out + (size_t)node * NFEAT + s * SLF))[q] = o;
        }
    }
}

// ------- fused pool (batch sorted, binary search) + FC head ---------
__global__ __launch_bounds__(256)
void poolfc_kernel(const float* __restrict__ H, const int* __restrict__ batch, int N,
                   const float* __restrict__ Wf1, const float* __restrict__ bf1,
                   const float* __restrict__ Wf2, const float* __restrict__ bf2,
                   float* __restrict__ out) {
    int g = blockIdx.x;

    int lo = 0, hi = N;
    while (lo < hi) { int mid = (lo + hi) >> 1; if (batch[mid] < g) lo = mid + 1; else hi = mid; }
    int start = lo;
    hi = N;
    while (lo < hi) { int mid = (lo + hi) >> 1; if (batch[mid] < g + 1) lo = mid + 1; else hi = mid; }
    int end = lo;

    int wave = threadIdx.x >> 6;
    int lane = threadIdx.x & 63;

    float2 acc = {0.f, 0.f};
    for (int i = start + wave; i < end; i += 4) {
        float2 v = ((const float2*)(H + (size_t)i * NFEAT))[lane];
        acc.x += v.x; acc.y += v.y;
    }

    __shared__ float2 part[4][64];
    __shared__ float hg[NFEAT];
    __shared__ float h1[FCH];
    part[wave][lane] = acc;
    __syncthreads();

    if (wave == 0) {
        float2 t0 = part[0][lane], t1 = part[1][lane], t2 = part[2][lane], t3 = part[3][lane];
        float c = fmaxf((float)(end - start), 1.0f);
        hg[lane * 2]     = (t0.x + t1.x + t2.x + t3.x) / c;
        hg[lane * 2 + 1] = (t0.y + t1.y + t2.y + t3.y) / c;
        float a = bf1[lane];
        #pragma unroll 4
        for (int k = 0; k < NFEAT; ++k) a = fmaf(hg[k], Wf1[k * FCH + lane], a);
        h1[lane] = fmaxf(a, 0.f);
        if (lane < NCLS) {
            float o = bf2[lane];
            #pragma unroll
            for (int j = 0; j < FCH; ++j) o = fmaf(h1[j], Wf2[j * NCLS + lane], o);
            out[g * NCLS + lane] = o;
        }
    }
}

extern "C" void kernel_launch(void* const* d_in, const int* in_sizes, int n_in,
                              void* d_out, int out_size, void* d_ws, size_t ws_size,
                              hipStream_t stream) {
    const float* x   = (const float*)d_in[0];
    const int*   ei  = (const int*)d_in[1];
    const int*   bat = (const int*)d_in[2];
    const float* W1  = (const float*)d_in[3];
    const float* b1  = (const float*)d_in[4];
    const float* W2  = (const float*)d_in[5];
    const float* b2  = (const float*)d_in[6];
    const float* W3  = (const float*)d_in[7];
    const float* b3  = (const float*)d_in[8];
    const float* Wf1 = (const float*)d_in[9];
    const float* bf1 = (const float*)d_in[10];
    const float* Wf2 = (const float*)d_in[11];
    const float* bf2 = (const float*)d_in[12];
    float* out = (float*)d_out;

    int N = in_sizes[0] / NFEAT;
    int E = in_sizes[1] / 2;
    const int* src = ei;
    const int* dst = ei + E;

    char* ws = (char*)d_ws;
    size_t off = 0;
    auto align256 = [](size_t v) { return (v + 255) & ~(size_t)255; };

    int* cursor = (int*)(ws + off);              // N ints (doubles as deg)
    off = align256(off + (size_t)N * 4);
    int* ell = (int*)(ws + off);                 // N*ELLW ints
    off = align256(off + (size_t)N * ELLW * 4);
    float* dinv = (float*)(ws + off);            // N floats
    off = align256(off + (size_t)N * 4);
    float* h0 = (float*)(ws + off);              // N*128 floats (slice-major h')
    off = align256(off + (size_t)N * NFEAT * 4);
    float* h1 = (float*)(ws + off);              // N*128 floats (row-major layer out)
    off = align256(off + (size_t)N * NFEAT * 4);

    hipMemsetAsync(cursor, 0, (size_t)N * 4, stream);

    int tpb = 256;
    int e4blocks = ((E + 3) / 4 + tpb - 1) / tpb;
    int nblocks = (N + tpb - 1) / tpb;

    ell_fill_kernel<<<e4blocks, tpb, 0, stream>>>(src, dst, E, cursor, ell);
    dinv_kernel<<<nblocks, tpb, 0, stream>>>(cursor, dinv, N);

    int gemm_blocks = (N + 127) / 128;
    int agg_blocks = ((N + AGG_CH - 1) / AGG_CH) * NSL;

    // layer 1
    gemm128_kernel<<<gemm_blocks, 256, 0, stream>>>(x, W1, dinv, h0, N);
    aggregate_kernel<<<agg_blocks, 256, 0, stream>>>(h0, cursor, ell, dinv, b1, h1, N);
    // layer 2
    gemm128_kernel<<<gemm_blocks, 256, 0, stream>>>(h1, W2, dinv, h0, N);
    aggregate_kernel<<<agg_blocks, 256, 0, stream>>>(h0, cursor, ell, dinv, b2, h1, N);
    // layer 3
    gemm128_kernel<<<gemm_blocks, 256, 0, stream>>>(h1, W3, dinv, h0, N);
    aggregate_kernel<<<agg_blocks, 256, 0, stream>>>(h0, cursor, ell, dinv, b3, h1, N);

    // fused pooling + head
    poolfc_kernel<<<NGRAPHS, 256, 0, stream>>>(h1, bat, N, Wf1, bf1, Wf2, bf2, out);
}

// Round 10
// 392.132 us; speedup vs baseline: 1.4122x; 1.4122x over previous
//
#include <hip/hip_runtime.h>

#define NFEAT 128
#define NGRAPHS 128
#define FCH 64
#define NCLS 10
#define ELLW 48

// ---------------- ELL fill: cursor[d]++ allocates slot --------------
__global__ void ell_fill_kernel(const int* __restrict__ src, const int* __restrict__ dst, int E,
                                int* __restrict__ cursor, int* __restrict__ ell) {
    int i = (blockIdx.x * blockDim.x + threadIdx.x) * 4;
    if (i + 3 < E) {
        int4 s4 = *(const int4*)(src + i);
        int4 d4 = *(const int4*)(dst + i);
        int p;
        p = atomicAdd(&cursor[d4.x], 1); if (p < ELLW) ell[(size_t)d4.x * ELLW + p] = s4.x;
        p = atomicAdd(&cursor[d4.y], 1); if (p < ELLW) ell[(size_t)d4.y * ELLW + p] = s4.y;
        p = atomicAdd(&cursor[d4.z], 1); if (p < ELLW) ell[(size_t)d4.z * ELLW + p] = s4.z;
        p = atomicAdd(&cursor[d4.w], 1); if (p < ELLW) ell[(size_t)d4.w * ELLW + p] = s4.w;
    } else {
        for (int j = i; j < E; ++j) {
            int d = dst[j];
            int p = atomicAdd(&cursor[d], 1);
            if (p < ELLW) ell[(size_t)d * ELLW + p] = src[j];
        }
    }
}

// ---------------- dinv = rsqrt(deg + 1) (self loop included) --------
__global__ void dinv_kernel(const int* __restrict__ deg, float* __restrict__ dinv, int N) {
    int i = blockIdx.x * blockDim.x + threadIdx.x;
    if (i < N) dinv[i] = rsqrtf((float)(deg[i] + 1));
}

// ---- GEMM: h'[r,:] = dinv[r] * (X[r,:] @ W), row-major output ------
// 256 threads, 128 rows x 128 cols per block, 8x8 micro-tile.
// W staged in 4 chunks of [32][128] (16 KB LDS -> 4+ blocks/CU).
// Lane cols: tx*4..+3 and 64+tx*4..+3  (2-way bank alias = free).
__global__ __launch_bounds__(256)
void gemm128_kernel(const float* __restrict__ X, const float* __restrict__ W,
                    const float* __restrict__ dinv, float* __restrict__ H, int N) {
    __shared__ float4 Ws4[32 * 32];  // 16 KB: 32 k-rows x 32 float4 (128 cols)
    int t = threadIdx.x;
    int tx = t & 15;   // col group
    int ty = t >> 4;   // row group: 8 rows
    int r0 = blockIdx.x * 128 + ty * 8;

    const float* xr[8];
    bool rowok[8];
    #pragma unroll
    for (int i = 0; i < 8; ++i) {
        rowok[i] = (r0 + i < N);
        xr[i] = X + (size_t)(rowok[i] ? (r0 + i) : 0) * NFEAT;
    }

    float acc[8][8];
    #pragma unroll
    for (int i = 0; i < 8; ++i)
        #pragma unroll
        for (int j = 0; j < 8; ++j) acc[i][j] = 0.f;

    const float4* W4 = (const float4*)W;

    for (int ko = 0; ko < 128; ko += 32) {
        // stage W rows ko..ko+31 (1024 float4, 4 per thread)
        #pragma unroll
        for (int i = 0; i < 4; ++i) Ws4[t + i * 256] = W4[ko * 32 + t + i * 256];
        __syncthreads();

        for (int k = 0; k < 32; k += 4) {
            float xk[8][4];
            #pragma unroll
            for (int i = 0; i < 8; ++i) {
                float4 v = *(const float4*)(xr[i] + ko + k);  // broadcast across 16 lanes
                xk[i][0] = v.x; xk[i][1] = v.y; xk[i][2] = v.z; xk[i][3] = v.w;
            }
            #pragma unroll
            for (int kk = 0; kk < 4; ++kk) {
                float4 wa = Ws4[(k + kk) * 32 + tx];        // cols tx*4..+3
                float4 wb = Ws4[(k + kk) * 32 + 16 + tx];   // cols 64+tx*4..+3
                float w[8] = {wa.x, wa.y, wa.z, wa.w, wb.x, wb.y, wb.z, wb.w};
                #pragma unroll
                for (int i = 0; i < 8; ++i) {
                    float xv = xk[i][kk];
                    #pragma unroll
                    for (int j = 0; j < 8; ++j) acc[i][j] = fmaf(xv, w[j], acc[i][j]);
                }
            }
        }
        __syncthreads();
    }

    #pragma unroll
    for (int i = 0; i < 8; ++i) {
        if (rowok[i]) {
            float di = dinv[r0 + i];
            float* hp = H + (size_t)(r0 + i) * NFEAT;
            float4 o0 = {di * acc[i][0], di * acc[i][1], di * acc[i][2], di * acc[i][3]};
            float4 o1 = {di * acc[i][4], di * acc[i][5], di * acc[i][6], di * acc[i][7]};
            *(float4*)(hp + tx * 4) = o0;
            *(float4*)(hp + 64 + tx * 4) = o1;
        }
    }
}

// ---------------- pull aggregation over ELL, prescaled H ------------
// out[i] = relu( dinv[i]*( h'[i] + sum_{s} h'[s] ) + b ),  h' = dinv*h
// float4/lane, 2 edges per wave-step (lanes 0-31 even edge, 32-63 odd).
__global__ __launch_bounds__(256)
void aggregate_kernel(const float* __restrict__ Hs, const int* __restrict__ deg,
                      const int* __restrict__ ell, const float* __restrict__ dinv,
                      const float* __restrict__ bias, float* __restrict__ out, int N) {
    int node = (blockIdx.x * 256 + threadIdx.x) >> 6;
    int lane = threadIdx.x & 63;
    if (node >= N) return;

    int half = lane >> 5;
    int fl = lane & 31;
    const float4* H4 = (const float4*)Hs;   // row stride = 32 float4

    float di = dinv[node];
    float4 acc = {0.f, 0.f, 0.f, 0.f};
    if (half == 0) acc = H4[(size_t)node * 32 + fl];   // self term h'_i

    const int* row = ell + (size_t)node * ELLW;
    int d = deg[node]; if (d > ELLW) d = ELLW;
    int e = 0;

    for (; e + 7 < d; e += 8) {
        int s0 = row[e + half], s1 = row[e + 2 + half];
        int s2 = row[e + 4 + half], s3 = row[e + 6 + half];
        float4 v0 = H4[(size_t)s0 * 32 + fl];
        float4 v1 = H4[(size_t)s1 * 32 + fl];
        float4 v2 = H4[(size_t)s2 * 32 + fl];
        float4 v3 = H4[(size_t)s3 * 32 + fl];
        acc.x += v0.x + v1.x + v2.x + v3.x;
        acc.y += v0.y + v1.y + v2.y + v3.y;
        acc.z += v0.z + v1.z + v2.z + v3.z;
        acc.w += v0.w + v1.w + v2.w + v3.w;
    }
    for (; e + 1 < d; e += 2) {
        int s = row[e + half];
        float4 v = H4[(size_t)s * 32 + fl];
        acc.x += v.x; acc.y += v.y; acc.z += v.z; acc.w += v.w;
    }
    if (e < d && half == 0) {
        int s = row[e];
        float4 v = H4[(size_t)s * 32 + fl];
        acc.x += v.x; acc.y += v.y; acc.z += v.z; acc.w += v.w;
    }

    acc.x += __shfl_down(acc.x, 32, 64);
    acc.y += __shfl_down(acc.y, 32, 64);
    acc.z += __shfl_down(acc.z, 32, 64);
    acc.w += __shfl_down(acc.w, 32, 64);

    if (half == 0) {
        float4 b = ((const float4*)bias)[fl];
        float4 o;
        o.x = fmaxf(fmaf(di, acc.x, b.x), 0.f);
        o.y = fmaxf(fmaf(di, acc.y, b.y), 0.f);
        o.z = fmaxf(fmaf(di, acc.z, b.z), 0.f);
        o.w = fmaxf(fmaf(di, acc.w, b.w), 0.f);
        ((float4*)(out + (size_t)node * NFEAT))[fl] = o;
    }
}

// ------- fused pool (batch sorted, binary search) + FC head ---------
__global__ __launch_bounds__(256)
void poolfc_kernel(const float* __restrict__ H, const int* __restrict__ batch, int N,
                   const float* __restrict__ Wf1, const float* __restrict__ bf1,
                   const float* __restrict__ Wf2, const float* __restrict__ bf2,
                   float* __restrict__ out) {
    int g = blockIdx.x;

    int lo = 0, hi = N;
    while (lo < hi) { int mid = (lo + hi) >> 1; if (batch[mid] < g) lo = mid + 1; else hi = mid; }
    int start = lo;
    hi = N;
    while (lo < hi) { int mid = (lo + hi) >> 1; if (batch[mid] < g + 1) lo = mid + 1; else hi = mid; }
    int end = lo;

    int wave = threadIdx.x >> 6;
    int lane = threadIdx.x & 63;

    float2 acc = {0.f, 0.f};
    for (int i = start + wave; i < end; i += 4) {
        float2 v = ((const float2*)(H + (size_t)i * NFEAT))[lane];
        acc.x += v.x; acc.y += v.y;
    }

    __shared__ float2 part[4][64];
    __shared__ float hg[NFEAT];
    __shared__ float h1[FCH];
    part[wave][lane] = acc;
    __syncthreads();

    if (wave == 0) {
        float2 t0 = part[0][lane], t1 = part[1][lane], t2 = part[2][lane], t3 = part[3][lane];
        float c = fmaxf((float)(end - start), 1.0f);
        hg[lane * 2]     = (t0.x + t1.x + t2.x + t3.x) / c;
        hg[lane * 2 + 1] = (t0.y + t1.y + t2.y + t3.y) / c;
        float a = bf1[lane];
        #pragma unroll 4
        for (int k = 0; k < NFEAT; ++k) a = fmaf(hg[k], Wf1[k * FCH + lane], a);
        h1[lane] = fmaxf(a, 0.f);
        if (lane < NCLS) {
            float o = bf2[lane];
            #pragma unroll
            for (int j = 0; j < FCH; ++j) o = fmaf(h1[j], Wf2[j * NCLS + lane], o);
            out[g * NCLS + lane] = o;
        }
    }
}

extern "C" void kernel_launch(void* const* d_in, const int* in_sizes, int n_in,
                              void* d_out, int out_size, void* d_ws, size_t ws_size,
                              hipStream_t stream) {
    const float* x   = (const float*)d_in[0];
    const int*   ei  = (const int*)d_in[1];
    const int*   bat = (const int*)d_in[2];
    const float* W1  = (const float*)d_in[3];
    const float* b1  = (const float*)d_in[4];
    const float* W2  = (const float*)d_in[5];
    const float* b2  = (const float*)d_in[6];
    const float* W3  = (const float*)d_in[7];
    const float* b3  = (const float*)d_in[8];
    const float* Wf1 = (const float*)d_in[9];
    const float* bf1 = (const float*)d_in[10];
    const float* Wf2 = (const float*)d_in[11];
    const float* bf2 = (const float*)d_in[12];
    float* out = (float*)d_out;

    int N = in_sizes[0] / NFEAT;
    int E = in_sizes[1] / 2;
    const int* src = ei;
    const int* dst = ei + E;

    char* ws = (char*)d_ws;
    size_t off = 0;
    auto align256 = [](size_t v) { return (v + 255) & ~(size_t)255; };

    int* cursor = (int*)(ws + off);              // N ints (doubles as deg)
    off = align256(off + (size_t)N * 4);
    int* ell = (int*)(ws + off);                 // N*ELLW ints
    off = align256(off + (size_t)N * ELLW * 4);
    float* dinv = (float*)(ws + off);            // N floats
    off = align256(off + (size_t)N * 4);
    float* h0 = (float*)(ws + off);              // N*128 floats (prescaled h')
    off = align256(off + (size_t)N * NFEAT * 4);
    float* h1 = (float*)(ws + off);              // N*128 floats (layer out)
    off = align256(off + (size_t)N * NFEAT * 4);

    hipMemsetAsync(cursor, 0, (size_t)N * 4, stream);

    int tpb = 256;
    int e4blocks = ((E + 3) / 4 + tpb - 1) / tpb;
    int nblocks = (N + tpb - 1) / tpb;

    ell_fill_kernel<<<e4blocks, tpb, 0, stream>>>(src, dst, E, cursor, ell);
    dinv_kernel<<<nblocks, tpb, 0, stream>>>(cursor, dinv, N);

    int gemm_blocks = (N + 127) / 128;
    int agg_blocks = (N + 3) / 4;  // 4 wave64 per 256-thread block

    // layer 1
    gemm128_kernel<<<gemm_blocks, 256, 0, stream>>>(x, W1, dinv, h0, N);
    aggregate_kernel<<<agg_blocks, 256, 0, stream>>>(h0, cursor, ell, dinv, b1, h1, N);
    // layer 2
    gemm128_kernel<<<gemm_blocks, 256, 0, stream>>>(h1, W2, dinv, h0, N);
    aggregate_kernel<<<agg_blocks, 256, 0, stream>>>(h0, cursor, ell, dinv, b2, h1, N);
    // layer 3
    gemm128_kernel<<<gemm_blocks, 256, 0, stream>>>(h1, W3, dinv, h0, N);
    aggregate_kernel<<<agg_blocks, 256, 0, stream>>>(h0, cursor, ell, dinv, b3, h1, N);

    // fused pooling + head
    poolfc_kernel<<<NGRAPHS, 256, 0, stream>>>(h1, bat, N, Wf1, bf1, Wf2, bf2, out);
}

// Round 12
// 390.412 us; speedup vs baseline: 1.4184x; 1.0044x over previous
//
#include <hip/hip_runtime.h>

#define NFEAT 128
#define NGRAPHS 128
#define FCH 64
#define NCLS 10
#define ELLW 48

// ---------------- ELL fill: cursor[d]++ allocates slot --------------
__global__ void ell_fill_kernel(const int* __restrict__ src, const int* __restrict__ dst, int E,
                                int* __restrict__ cursor, int* __restrict__ ell) {
    int i = (blockIdx.x * blockDim.x + threadIdx.x) * 4;
    if (i + 3 < E) {
        int4 s4 = *(const int4*)(src + i);
        int4 d4 = *(const int4*)(dst + i);
        int p;
        p = atomicAdd(&cursor[d4.x], 1); if (p < ELLW) ell[(size_t)d4.x * ELLW + p] = s4.x;
        p = atomicAdd(&cursor[d4.y], 1); if (p < ELLW) ell[(size_t)d4.y * ELLW + p] = s4.y;
        p = atomicAdd(&cursor[d4.z], 1); if (p < ELLW) ell[(size_t)d4.z * ELLW + p] = s4.z;
        p = atomicAdd(&cursor[d4.w], 1); if (p < ELLW) ell[(size_t)d4.w * ELLW + p] = s4.w;
    } else {
        for (int j = i; j < E; ++j) {
            int d = dst[j];
            int p = atomicAdd(&cursor[d], 1);
            if (p < ELLW) ell[(size_t)d * ELLW + p] = src[j];
        }
    }
}

// ---------------- dinv = rsqrt(deg + 1) (self loop included) --------
__global__ void dinv_kernel(const int* __restrict__ deg, float* __restrict__ dinv, int N) {
    int i = blockIdx.x * blockDim.x + threadIdx.x;
    if (i < N) dinv[i] = rsqrtf((float)(deg[i] + 1));
}

// ---- GEMM: h'[r,:] = dinv[r] * (X[r,:] @ W), row-major output ------
// 64 rows x 128 cols per block (grid = ceil(N/64) = 782 blocks, ALL
// resident: 32 KB LDS -> 4 blocks/CU, 16 waves/CU, no round quantization).
// W staged in 2 phases of 64 k-rows (32 KB). 4x8 micro-tile.
// Lane cols: tx*4..+3 and 64+tx*4..+3 (2-way bank alias = free).
__global__ __launch_bounds__(256)
void gemm128_kernel(const float* __restrict__ X, const float* __restrict__ W,
                    const float* __restrict__ dinv, float* __restrict__ H, int N) {
    __shared__ float4 Ws4[64 * 32];  // 32 KB: 64 k-rows x 32 float4
    int t = threadIdx.x;
    int tx = t & 15;   // col group
    int ty = t >> 4;   // row group: 4 rows
    int r0 = blockIdx.x * 64 + ty * 4;

    const float* xr[4];
    bool rowok[4];
    #pragma unroll
    for (int i = 0; i < 4; ++i) {
        rowok[i] = (r0 + i < N);
        xr[i] = X + (size_t)(rowok[i] ? (r0 + i) : 0) * NFEAT;
    }

    float acc[4][8];
    #pragma unroll
    for (int i = 0; i < 4; ++i)
        #pragma unroll
        for (int j = 0; j < 8; ++j) acc[i][j] = 0.f;

    const float4* W4 = (const float4*)W;

    #pragma unroll
    for (int ph = 0; ph < 2; ++ph) {
        // stage W k-rows ph*64 .. ph*64+63 (2048 float4, 8 per thread)
        #pragma unroll
        for (int i = 0; i < 8; ++i) Ws4[t + i * 256] = W4[ph * 2048 + t + i * 256];
        __syncthreads();

        for (int k = 0; k < 64; k += 4) {
            float xk[4][4];
            #pragma unroll
            for (int i = 0; i < 4; ++i) {
                float4 v = *(const float4*)(xr[i] + ph * 64 + k);  // broadcast across 16 lanes
                xk[i][0] = v.x; xk[i][1] = v.y; xk[i][2] = v.z; xk[i][3] = v.w;
            }
            #pragma unroll
            for (int kk = 0; kk < 4; ++kk) {
                float4 wa = Ws4[(k + kk) * 32 + tx];        // cols tx*4..+3
                float4 wb = Ws4[(k + kk) * 32 + 16 + tx];   // cols 64+tx*4..+3
                float w[8] = {wa.x, wa.y, wa.z, wa.w, wb.x, wb.y, wb.z, wb.w};
                #pragma unroll
                for (int i = 0; i < 4; ++i) {
                    float xv = xk[i][kk];
                    #pragma unroll
                    for (int j = 0; j < 8; ++j) acc[i][j] = fmaf(xv, w[j], acc[i][j]);
                }
            }
        }
        __syncthreads();
    }

    #pragma unroll
    for (int i = 0; i < 4; ++i) {
        if (rowok[i]) {
            float di = dinv[r0 + i];
            float* hp = H + (size_t)(r0 + i) * NFEAT;
            float4 o0 = {di * acc[i][0], di * acc[i][1], di * acc[i][2], di * acc[i][3]};
            float4 o1 = {di * acc[i][4], di * acc[i][5], di * acc[i][6], di * acc[i][7]};
            *(float4*)(hp + tx * 4) = o0;
            *(float4*)(hp + 64 + tx * 4) = o1;
        }
    }
}

// ---------------- pull aggregation over ELL, prescaled H ------------
// out[i] = relu( dinv[i]*( h'[i] + sum_{s} h'[s] ) + b ),  h' = dinv*h
// float4/lane, 2 edges per wave-step (lanes 0-31 even edge, 32-63 odd).
__global__ __launch_bounds__(256)
void aggregate_kernel(const float* __restrict__ Hs, const int* __restrict__ deg,
                      const int* __restrict__ ell, const float* __restrict__ dinv,
                      const float* __restrict__ bias, float* __restrict__ out, int N) {
    int node = (blockIdx.x * 256 + threadIdx.x) >> 6;
    int lane = threadIdx.x & 63;
    if (node >= N) return;

    int half = lane >> 5;
    int fl = lane & 31;
    const float4* H4 = (const float4*)Hs;   // row stride = 32 float4

    float di = dinv[node];
    float4 acc = {0.f, 0.f, 0.f, 0.f};
    if (half == 0) acc = H4[(size_t)node * 32 + fl];   // self term h'_i

    const int* row = ell + (size_t)node * ELLW;
    int d = deg[node]; if (d > ELLW) d = ELLW;
    int e = 0;

    for (; e + 7 < d; e += 8) {
        int s0 = row[e + half], s1 = row[e + 2 + half];
        int s2 = row[e + 4 + half], s3 = row[e + 6 + half];
        float4 v0 = H4[(size_t)s0 * 32 + fl];
        float4 v1 = H4[(size_t)s1 * 32 + fl];
        float4 v2 = H4[(size_t)s2 * 32 + fl];
        float4 v3 = H4[(size_t)s3 * 32 + fl];
        acc.x += v0.x + v1.x + v2.x + v3.x;
        acc.y += v0.y + v1.y + v2.y + v3.y;
        acc.z += v0.z + v1.z + v2.z + v3.z;
        acc.w += v0.w + v1.w + v2.w + v3.w;
    }
    for (; e + 1 < d; e += 2) {
        int s = row[e + half];
        float4 v = H4[(size_t)s * 32 + fl];
        acc.x += v.x; acc.y += v.y; acc.z += v.z; acc.w += v.w;
    }
    if (e < d && half == 0) {
        int s = row[e];
        float4 v = H4[(size_t)s * 32 + fl];
        acc.x += v.x; acc.y += v.y; acc.z += v.z; acc.w += v.w;
    }

    acc.x += __shfl_down(acc.x, 32, 64);
    acc.y += __shfl_down(acc.y, 32, 64);
    acc.z += __shfl_down(acc.z, 32, 64);
    acc.w += __shfl_down(acc.w, 32, 64);

    if (half == 0) {
        float4 b = ((const float4*)bias)[fl];
        float4 o;
        o.x = fmaxf(fmaf(di, acc.x, b.x), 0.f);
        o.y = fmaxf(fmaf(di, acc.y, b.y), 0.f);
        o.z = fmaxf(fmaf(di, acc.z, b.z), 0.f);
        o.w = fmaxf(fmaf(di, acc.w, b.w), 0.f);
        ((float4*)(out + (size_t)node * NFEAT))[fl] = o;
    }
}

// ------- fused pool (batch sorted, binary search) + FC head ---------
__global__ __launch_bounds__(256)
void poolfc_kernel(const float* __restrict__ H, const int* __restrict__ batch, int N,
                   const float* __restrict__ Wf1, const float* __restrict__ bf1,
                   const float* __restrict__ Wf2, const float* __restrict__ bf2,
                   float* __restrict__ out) {
    int g = blockIdx.x;

    int lo = 0, hi = N;
    while (lo < hi) { int mid = (lo + hi) >> 1; if (batch[mid] < g) lo = mid + 1; else hi = mid; }
    int start = lo;
    hi = N;
    while (lo < hi) { int mid = (lo + hi) >> 1; if (batch[mid] < g + 1) lo = mid + 1; else hi = mid; }
    int end = lo;

    int wave = threadIdx.x >> 6;
    int lane = threadIdx.x & 63;

    float2 acc = {0.f, 0.f};
    for (int i = start + wave; i < end; i += 4) {
        float2 v = ((const float2*)(H + (size_t)i * NFEAT))[lane];
        acc.x += v.x; acc.y += v.y;
    }

    __shared__ float2 part[4][64];
    __shared__ float hg[NFEAT];
    __shared__ float h1[FCH];
    part[wave][lane] = acc;
    __syncthreads();

    if (wave == 0) {
        float2 t0 = part[0][lane], t1 = part[1][lane], t2 = part[2][lane], t3 = part[3][lane];
        float c = fmaxf((float)(end - start), 1.0f);
        hg[lane * 2]     = (t0.x + t1.x + t2.x + t3.x) / c;
        hg[lane * 2 + 1] = (t0.y + t1.y + t2.y + t3.y) / c;
        float a = bf1[lane];
        #pragma unroll 4
        for (int k = 0; k < NFEAT; ++k) a = fmaf(hg[k], Wf1[k * FCH + lane], a);
        h1[lane] = fmaxf(a, 0.f);
        if (lane < NCLS) {
            float o = bf2[lane];
            #pragma unroll
            for (int j = 0; j < FCH; ++j) o = fmaf(h1[j], Wf2[j * NCLS + lane], o);
            out[g * NCLS + lane] = o;
        }
    }
}

extern "C" void kernel_launch(void* const* d_in, const int* in_sizes, int n_in,
                              void* d_out, int out_size, void* d_ws, size_t ws_size,
                              hipStream_t stream) {
    const float* x   = (const float*)d_in[0];
    const int*   ei  = (const int*)d_in[1];
    const int*   bat = (const int*)d_in[2];
    const float* W1  = (const float*)d_in[3];
    const float* b1  = (const float*)d_in[4];
    const float* W2  = (const float*)d_in[5];
    const float* b2  = (const float*)d_in[6];
    const float* W3  = (const float*)d_in[7];
    const float* b3  = (const float*)d_in[8];
    const float* Wf1 = (const float*)d_in[9];
    const float* bf1 = (const float*)d_in[10];
    const float* Wf2 = (const float*)d_in[11];
    const float* bf2 = (const float*)d_in[12];
    float* out = (float*)d_out;

    int N = in_sizes[0] / NFEAT;
    int E = in_sizes[1] / 2;
    const int* src = ei;
    const int* dst = ei + E;

    char* ws = (char*)d_ws;
    size_t off = 0;
    auto align256 = [](size_t v) { return (v + 255) & ~(size_t)255; };

    int* cursor = (int*)(ws + off);              // N ints (doubles as deg)
    off = align256(off + (size_t)N * 4);
    int* ell = (int*)(ws + off);                 // N*ELLW ints
    off = align256(off + (size_t)N * ELLW * 4);
    float* dinv = (float*)(ws + off);            // N floats
    off = align256(off + (size_t)N * 4);
    float* h0 = (float*)(ws + off);              // N*128 floats (prescaled h')
    off = align256(off + (size_t)N * NFEAT * 4);
    float* h1 = (float*)(ws + off);              // N*128 floats (layer out)
    off = align256(off + (size_t)N * NFEAT * 4);

    hipMemsetAsync(cursor, 0, (size_t)N * 4, stream);

    int tpb = 256;
    int e4blocks = ((E + 3) / 4 + tpb - 1) / tpb;
    int nblocks = (N + tpb - 1) / tpb;

    ell_fill_kernel<<<e4blocks, tpb, 0, stream>>>(src, dst, E, cursor, ell);
    dinv_kernel<<<nblocks, tpb, 0, stream>>>(cursor, dinv, N);

    int gemm_blocks = (N + 63) / 64;
    int agg_blocks = (N + 3) / 4;  // 4 wave64 per 256-thread block

    // layer 1
    gemm128_kernel<<<gemm_blocks, 256, 0, stream>>>(x, W1, dinv, h0, N);
    aggregate_kernel<<<agg_blocks, 256, 0, stream>>>(h0, cursor, ell, dinv, b1, h1, N);
    // layer 2
    gemm128_kernel<<<gemm_blocks, 256, 0, stream>>>(h1, W2, dinv, h0, N);
    aggregate_kernel<<<agg_blocks, 256, 0, stream>>>(h0, cursor, ell, dinv, b2, h1, N);
    // layer 3
    gemm128_kernel<<<gemm_blocks, 256, 0, stream>>>(h1, W3, dinv, h0, N);
    aggregate_kernel<<<agg_blocks, 256, 0, stream>>>(h0, cursor, ell, dinv, b3, h1, N);

    // fused pooling + head
    poolfc_kernel<<<NGRAPHS, 256, 0, stream>>>(h1, bat, N, Wf1, bf1, Wf2, bf2, out);
}